// Round 8
// baseline (147.830 us; speedup 1.0000x reference)
//
#include <hip/hip_runtime.h>

#define N_SAMPLES 4096
#define D_IN      128
#define R_RULES   256
#define O_OUT     64
#define KPAD      136
#define NCHUNK    17
#define CH_I      8
#define NGROUPS   8

typedef _Float16 f16;
typedef _Float16 f16x2 __attribute__((ext_vector_type(2)));
typedef _Float16 f16x4 __attribute__((ext_vector_type(4)));
typedef _Float16 f16x8 __attribute__((ext_vector_type(8)));
typedef float    f32x4 __attribute__((ext_vector_type(4)));

// ---------------------------------------------------------------------------
// Kernel 1 (R6 verbatim): fused prep.  Blocks [0,1088): permute coeffs fp32
// -> fp16 Cp[g][i][j][rg].  Blocks [1088,1216): build Bext (Markidis split).
// ---------------------------------------------------------------------------
__global__ __launch_bounds__(256) void anfis_prep_all(
    const float* __restrict__ coeffs, const float* __restrict__ centers,
    const float* __restrict__ sigmas, f16* __restrict__ Cp,
    f16* __restrict__ Bext) {
  __shared__ alignas(16) f16 T[64 * 32];
  __shared__ float red[4];
  const int bid = blockIdx.x;
  const int tid = threadIdx.x;

  if (bid < 1088) {
    const int g = bid / 136;
    const int i = bid - g * 136;
    const int rg = tid & 31;
    const int jb = tid >> 5;
    if (i < 129) {
      const float* src = coeffs + ((size_t)(g * 32 + rg) * 129 + i) * 64 + jb * 8;
      float4 a = reinterpret_cast<const float4*>(src)[0];
      float4 b = reinterpret_cast<const float4*>(src)[1];
      T[(jb * 8 + 0) * 32 + rg] = (f16)a.x;
      T[(jb * 8 + 1) * 32 + rg] = (f16)a.y;
      T[(jb * 8 + 2) * 32 + rg] = (f16)a.z;
      T[(jb * 8 + 3) * 32 + rg] = (f16)a.w;
      T[(jb * 8 + 4) * 32 + rg] = (f16)b.x;
      T[(jb * 8 + 5) * 32 + rg] = (f16)b.y;
      T[(jb * 8 + 6) * 32 + rg] = (f16)b.z;
      T[(jb * 8 + 7) * 32 + rg] = (f16)b.w;
    } else {
#pragma unroll
      for (int q = 0; q < 8; ++q) T[(jb * 8 + q) * 32 + rg] = (f16)0.0f;
    }
    __syncthreads();
    f16x8* dst = reinterpret_cast<f16x8*>(Cp + ((size_t)g * KPAD + i) * 2048);
    dst[tid] = reinterpret_cast<const f16x8*>(T)[tid];
  } else {
    const int sub = tid >> 7;
    const int d = tid & 127;
    const int r = ((bid - 1088) << 1) + sub;
    const float c = centers[(size_t)r * 128 + d];
    const float s = sigmas[(size_t)r * 128 + d];
    const float iv = 0.5f / (s * s);
    const float b1 = -iv;
    const float b2 = 2.0f * c * iv;
    f16 b1h = (f16)b1; f16 b1l = (f16)(b1 - (float)b1h);
    f16 b2h = (f16)b2; f16 b2l = (f16)(b2 - (float)b2h);
    auto put = [&](int k, f16 v) {
      Bext[((size_t)(k >> 3) * 256 + r) * 8 + (k & 7)] = v;
    };
    put(d, b1h);
    put(128 + d, b1l);
    put(256 + d, b1h);
    put(384 + d, b2h);
    put(512 + d, b2l);
    put(640 + d, b2h);
    float p = -c * c * iv;
#pragma unroll
    for (int off = 32; off; off >>= 1) p += __shfl_xor(p, off, 64);
    if ((tid & 63) == 0) red[tid >> 6] = p;
    __syncthreads();
    if (d < 30) put(770 + d, (f16)0.0f);
    if (d == 0) {
      float k2 = red[sub * 2] + red[sub * 2 + 1];
      f16 h = (f16)k2; f16 l = (f16)(k2 - (float)h);
      put(768, h);
      put(769, l);
    }
  }
}

// ---------------------------------------------------------------------------
// Kernel 2 (R6 verbatim + cnt zeroing): strengths + normalization fused.
// ---------------------------------------------------------------------------
__global__ __launch_bounds__(512) void anfis_s16n(
    const float* __restrict__ X, const f16* __restrict__ Bext,
    f16* __restrict__ P, int* __restrict__ cnt) {
  __shared__ alignas(16) f16 Xq[16 * 512];
  __shared__ float rowsum[16][8];
  const int tid = threadIdx.x;
  const int m0 = blockIdx.x * 16;
  const int w = tid >> 6, lane = tid & 63;
  const int lm = lane & 15, quad = lane >> 4;

  if (blockIdx.x == 0 && tid < 64) cnt[tid] = 0;   // for main16's last-block

  if (tid < 256) {
    int m = tid >> 4, oct = tid & 15;
    const float* src = X + (size_t)(m0 + m) * 128 + oct * 8;
    float4 a = reinterpret_cast<const float4*>(src)[0];
    float4 b = reinterpret_cast<const float4*>(src)[1];
    float xs[8] = {a.x, a.y, a.z, a.w, b.x, b.y, b.z, b.w};
    f16x8 vh, vl, v2h, v2l;
#pragma unroll
    for (int q = 0; q < 8; ++q) {
      float x = xs[q];
      f16 h = (f16)x;   f16 l = (f16)(x - (float)h);
      float x2 = x * x;
      f16 h2 = (f16)x2; f16 l2 = (f16)(x2 - (float)h2);
      vh[q] = h; vl[q] = l; v2h[q] = h2; v2l[q] = l2;
    }
    f16x8* row = reinterpret_cast<f16x8*>(&Xq[m * 512]);
    int sw = m & 7;
    row[(0 * 16 + oct) ^ sw] = v2h;
    row[(1 * 16 + oct) ^ sw] = v2l;
    row[(2 * 16 + oct) ^ sw] = vh;
    row[(3 * 16 + oct) ^ sw] = vl;
  }
  __syncthreads();

  f32x4 acc[2] = {};
  const f16x8* arow = reinterpret_cast<const f16x8*>(&Xq[lm * 512]);
  const int asw = lm & 7;
  const int col0 = w * 32 + lm;

#pragma unroll
  for (int t = 0; t < 24; ++t) {
    const int seg = t >> 2;
    const int plane = (seg < 2) ? 0 : (seg == 2) ? 1 : (seg < 5) ? 2 : 3;
    const int o = t * 4 + quad;
    f16x8 av = arow[(plane * 16 + (o & 15)) ^ asw];
    const f16* bp = Bext + ((size_t)o * 256 + col0) * 8;
    f16x8 b0 = *reinterpret_cast<const f16x8*>(bp);
    f16x8 b1 = *reinterpret_cast<const f16x8*>(bp + 16 * 8);
    acc[0] = __builtin_amdgcn_mfma_f32_16x16x32_f16(av, b0, acc[0], 0, 0, 0);
    acc[1] = __builtin_amdgcn_mfma_f32_16x16x32_f16(av, b1, acc[1], 0, 0, 0);
  }
  {
    f16x8 av = {};
    if (quad == 0) { av[0] = (f16)1.0f; av[1] = (f16)1.0f; }
    const int o = 96 + quad;
    const f16* bp = Bext + ((size_t)o * 256 + col0) * 8;
    f16x8 b0 = *reinterpret_cast<const f16x8*>(bp);
    f16x8 b1 = *reinterpret_cast<const f16x8*>(bp + 16 * 8);
    acc[0] = __builtin_amdgcn_mfma_f32_16x16x32_f16(av, b0, acc[0], 0, 0, 0);
    acc[1] = __builtin_amdgcn_mfma_f32_16x16x32_f16(av, b1, acc[1], 0, 0, 0);
  }

  float e[2][4];
#pragma unroll
  for (int nf = 0; nf < 2; ++nf)
#pragma unroll
    for (int q = 0; q < 4; ++q) e[nf][q] = __expf(acc[nf][q]);

  float rp[4];
#pragma unroll
  for (int q = 0; q < 4; ++q) {
    rp[q] = e[0][q] + e[1][q];
#pragma unroll
    for (int msk = 1; msk < 16; msk <<= 1) rp[q] += __shfl_xor(rp[q], msk, 64);
  }
  if (lm == 0)
#pragma unroll
    for (int q = 0; q < 4; ++q) rowsum[quad * 4 + q][w] = rp[q];
  __syncthreads();

#pragma unroll
  for (int q = 0; q < 4; ++q) {
    const int row = quad * 4 + q;
    float s8 = 0.f;
#pragma unroll
    for (int w2 = 0; w2 < 8; ++w2) s8 += rowsum[row][w2];
    const float inv = 1.0f / (s8 + 1e-8f);
#pragma unroll
    for (int nf = 0; nf < 2; ++nf)
      P[(size_t)(m0 + row) * R_RULES + w * 32 + nf * 16 + lm] =
          (f16)(e[nf][q] * inv);
  }
}

// ---------------------------------------------------------------------------
// Kernel 3: rules GEMM (R6-proven body) + fused softmax finish via
// last-block-per-mtile (device-scope atomics + fences; no dispatch-order
// assumption, no spinning).  The 8th g-block to finish an m-tile combines
// the 8 partials and writes the softmax output for its 64 rows.
// ---------------------------------------------------------------------------
__global__ __launch_bounds__(256) void anfis_main16(
    const float* __restrict__ X, const f16* __restrict__ P,
    const f16* __restrict__ Cp, float* __restrict__ part,
    int* __restrict__ cnt, float* __restrict__ out) {
  __shared__ alignas(16) f16 Xs[64 * KPAD];          // [m][i], 17408 B
  __shared__ alignas(16) f16 Bs[CH_I * 64 * 32];     // [ii][j][rg] 32768 B
  __shared__ int lastflag;
  const int tid = threadIdx.x;
  const int g = blockIdx.x & 7;
  const int mt = blockIdx.x >> 3;
  const int m0 = mt * 64;
  const int w = tid >> 6, lane = tid & 63;
  const int mg = w >> 1, ng = w & 1;
  const int lm = lane & 15, quad = lane >> 4;

#pragma unroll
  for (int it = 0; it < 8; ++it) {
    int fi = tid + (it << 8);
    int m = fi >> 5, k4 = (fi & 31) << 2;
    float4 v = reinterpret_cast<const float4*>(X)[(size_t)(m0 + m) * 32 + (fi & 31)];
    f16x4 h = {(f16)v.x, (f16)v.y, (f16)v.z, (f16)v.w};
    *reinterpret_cast<f16x4*>(&Xs[m * KPAD + k4]) = h;
  }
  if (tid < 64) {
    f16x8 bias = {};
    bias[0] = (f16)1.0f;
    *reinterpret_cast<f16x8*>(&Xs[tid * KPAD + 128]) = bias;
  }

  union F8 { f16x8 v; f16x2 h[4]; };
  F8 pf[2];
#pragma unroll
  for (int mf = 0; mf < 2; ++mf) {
    int row = m0 + mg * 32 + mf * 16 + lm;
    pf[mf].v = *reinterpret_cast<const f16x8*>(
        &P[(size_t)row * R_RULES + g * 32 + quad * 8]);
  }

  f32x4 acc[2][2] = {};
  const char* cpg = (const char*)Cp + (size_t)g * KPAD * 4096;

  for (int c = 0; c < NCHUNK; ++c) {
    __syncthreads();
    const char* gsrc = cpg + (size_t)c * 32768;
#pragma unroll
    for (int it = 0; it < 8; ++it) {
      int off = (it << 12) + (w << 10);
      __builtin_amdgcn_global_load_lds(
          (const __attribute__((address_space(1))) unsigned int*)(gsrc + off + lane * 16),
          (__attribute__((address_space(3))) unsigned int*)((char*)Bs + off),
          16, 0, 0);
    }
    __syncthreads();
    f16x8 xv[2];
    xv[0] = *reinterpret_cast<const f16x8*>(&Xs[(mg * 32 + lm) * KPAD + c * 8]);
    xv[1] = *reinterpret_cast<const f16x8*>(&Xs[(mg * 32 + 16 + lm) * KPAD + c * 8]);
#pragma unroll
    for (int ii = 0; ii < CH_I; ++ii) {
      F8 a[2];
#pragma unroll
      for (int mf = 0; mf < 2; ++mf) {
        f16 xvv = xv[mf][ii];
        f16x2 xd = {xvv, xvv};
        a[mf].h[0] = pf[mf].h[0] * xd;
        a[mf].h[1] = pf[mf].h[1] * xd;
        a[mf].h[2] = pf[mf].h[2] * xd;
        a[mf].h[3] = pf[mf].h[3] * xd;
      }
      const f16* brow = &Bs[(ii * 64 + ng * 32 + lm) * 32 + quad * 8];
      f16x8 b0 = *reinterpret_cast<const f16x8*>(brow);
      f16x8 b1 = *reinterpret_cast<const f16x8*>(brow + 16 * 32);
      acc[0][0] = __builtin_amdgcn_mfma_f32_16x16x32_f16(a[0].v, b0, acc[0][0], 0, 0, 0);
      acc[0][1] = __builtin_amdgcn_mfma_f32_16x16x32_f16(a[0].v, b1, acc[0][1], 0, 0, 0);
      acc[1][0] = __builtin_amdgcn_mfma_f32_16x16x32_f16(a[1].v, b0, acc[1][0], 0, 0, 0);
      acc[1][1] = __builtin_amdgcn_mfma_f32_16x16x32_f16(a[1].v, b1, acc[1][1], 0, 0, 0);
    }
  }

#pragma unroll
  for (int mf = 0; mf < 2; ++mf)
#pragma unroll
    for (int nf = 0; nf < 2; ++nf)
#pragma unroll
      for (int q = 0; q < 4; ++q) {
        int row = m0 + mg * 32 + mf * 16 + quad * 4 + q;
        int col = ng * 32 + nf * 16 + lm;
        part[((size_t)g * N_SAMPLES + row) * O_OUT + col] = acc[mf][nf][q];
      }

  // ---- last-block-per-mtile softmax finish ----
  __syncthreads();                 // all part stores issued & drained
  if (tid == 0) {
    __threadfence();               // release: part visible device-wide
    int old = atomicAdd(&cnt[mt], 1);
    lastflag = (old == 7);
  }
  __syncthreads();
  if (lastflag) {
    __threadfence();               // acquire: invalidate stale cached lines
    const size_t stride = (size_t)N_SAMPLES * O_OUT;
#pragma unroll 1
    for (int it2 = 0; it2 < 16; ++it2) {
      const int n = m0 + it2 * 4 + (tid >> 6);
      const float* p0 = part + (size_t)n * O_OUT + lane;
      float v = 0.f;
#pragma unroll
      for (int gg = 0; gg < 8; ++gg) v += p0[gg * stride];
      float mx = v;
#pragma unroll
      for (int off = 32; off; off >>= 1) mx = fmaxf(mx, __shfl_xor(mx, off, 64));
      float e = __expf(v - mx);
      float s = e;
#pragma unroll
      for (int off = 32; off; off >>= 1) s += __shfl_xor(s, off, 64);
      out[(size_t)n * O_OUT + lane] = e / s;
    }
  }
}

extern "C" void kernel_launch(void* const* d_in, const int* in_sizes, int n_in,
                              void* d_out, int out_size, void* d_ws, size_t ws_size,
                              hipStream_t stream) {
  const float* X       = (const float*)d_in[0];
  const float* centers = (const float*)d_in[1];
  const float* sigmas  = (const float*)d_in[2];
  const float* coeffs  = (const float*)d_in[3];
  float* out = (float*)d_out;

  float* part = (float*)d_ws;                                   // 8 MB
  f16*   Cp   = (f16*)(part + (size_t)NGROUPS * N_SAMPLES * O_OUT);
  f16*   Bext = Cp + (size_t)NGROUPS * KPAD * 2048;             // 400 KB
  f16*   P    = Bext + (size_t)100 * 256 * 8;                   // 2 MB
  int*   cnt  = (int*)(P + (size_t)N_SAMPLES * R_RULES);        // 256 B

  anfis_prep_all<<<1088 + 128, 256, 0, stream>>>(coeffs, centers, sigmas, Cp, Bext);
  anfis_s16n<<<N_SAMPLES / 16, 512, 0, stream>>>(X, Bext, P, cnt);
  anfis_main16<<<512, 256, 0, stream>>>(X, P, Cp, part, cnt, out);
}

// Round 9
// 103.026 us; speedup vs baseline: 1.4349x; 1.4349x over previous
//
#include <hip/hip_runtime.h>

#define N_SAMPLES 4096
#define D_IN      128
#define R_RULES   256
#define O_OUT     64
#define KPAD      136
#define NCHUNK    17
#define CH_I      8
#define NGROUPS   8

typedef _Float16 f16;
typedef _Float16 f16x2 __attribute__((ext_vector_type(2)));
typedef _Float16 f16x4 __attribute__((ext_vector_type(4)));
typedef _Float16 f16x8 __attribute__((ext_vector_type(8)));
typedef float    f32x4 __attribute__((ext_vector_type(4)));

// ---------------------------------------------------------------------------
// Kernel 1: fused prep.  Blocks [0,1088): permute coeffs fp32 -> fp16
// Cp[g][i][j][blk^((j>>1)&3)][rg&7]  -- the 16B sub-blocks of each 64B j-row
// are XOR-swizzled so that main16's ds_read_b128 pattern is bank-conflict-
// free after the (layout-preserving) global_load_lds staging memcpy.
// Blocks [1088,1216): build Bext (Markidis split) for the strengths GEMM.
// ---------------------------------------------------------------------------
__global__ __launch_bounds__(256) void anfis_prep_all(
    const float* __restrict__ coeffs, const float* __restrict__ centers,
    const float* __restrict__ sigmas, f16* __restrict__ Cp,
    f16* __restrict__ Bext) {
  __shared__ alignas(16) f16 T[64 * 32];
  __shared__ float red[4];
  const int bid = blockIdx.x;
  const int tid = threadIdx.x;

  if (bid < 1088) {
    const int g = bid / 136;
    const int i = bid - g * 136;
    const int rg = tid & 31;
    const int jb = tid >> 5;
    if (i < 129) {
      const float* src = coeffs + ((size_t)(g * 32 + rg) * 129 + i) * 64 + jb * 8;
      float4 a = reinterpret_cast<const float4*>(src)[0];
      float4 b = reinterpret_cast<const float4*>(src)[1];
      T[(jb * 8 + 0) * 32 + rg] = (f16)a.x;
      T[(jb * 8 + 1) * 32 + rg] = (f16)a.y;
      T[(jb * 8 + 2) * 32 + rg] = (f16)a.z;
      T[(jb * 8 + 3) * 32 + rg] = (f16)a.w;
      T[(jb * 8 + 4) * 32 + rg] = (f16)b.x;
      T[(jb * 8 + 5) * 32 + rg] = (f16)b.y;
      T[(jb * 8 + 6) * 32 + rg] = (f16)b.z;
      T[(jb * 8 + 7) * 32 + rg] = (f16)b.w;
    } else {
#pragma unroll
      for (int q = 0; q < 8; ++q) T[(jb * 8 + q) * 32 + rg] = (f16)0.0f;
    }
    __syncthreads();
    // tid -> (j = tid>>2, blk = tid&3); store blk at blk ^ ((j>>1)&3)
    f16x8* dst = reinterpret_cast<f16x8*>(Cp + ((size_t)g * KPAD + i) * 2048);
    const int j = tid >> 2, blk = tid & 3;
    dst[(j << 2) | (blk ^ ((j >> 1) & 3))] = reinterpret_cast<const f16x8*>(T)[tid];
  } else {
    const int sub = tid >> 7;
    const int d = tid & 127;
    const int r = ((bid - 1088) << 1) + sub;
    const float c = centers[(size_t)r * 128 + d];
    const float s = sigmas[(size_t)r * 128 + d];
    const float iv = 0.5f / (s * s);
    const float b1 = -iv;
    const float b2 = 2.0f * c * iv;
    f16 b1h = (f16)b1; f16 b1l = (f16)(b1 - (float)b1h);
    f16 b2h = (f16)b2; f16 b2l = (f16)(b2 - (float)b2h);
    auto put = [&](int k, f16 v) {
      Bext[((size_t)(k >> 3) * 256 + r) * 8 + (k & 7)] = v;
    };
    put(d, b1h);
    put(128 + d, b1l);
    put(256 + d, b1h);
    put(384 + d, b2h);
    put(512 + d, b2l);
    put(640 + d, b2h);
    float p = -c * c * iv;
#pragma unroll
    for (int off = 32; off; off >>= 1) p += __shfl_xor(p, off, 64);
    if ((tid & 63) == 0) red[tid >> 6] = p;
    __syncthreads();
    if (d < 30) put(770 + d, (f16)0.0f);
    if (d == 0) {
      float k2 = red[sub * 2] + red[sub * 2 + 1];
      f16 h = (f16)k2; f16 l = (f16)(k2 - (float)h);
      put(768, h);
      put(769, l);
    }
  }
}

// ---------------------------------------------------------------------------
// Kernel 2 (R6 verbatim): strengths + normalization fused.
// ---------------------------------------------------------------------------
__global__ __launch_bounds__(512) void anfis_s16n(
    const float* __restrict__ X, const f16* __restrict__ Bext,
    f16* __restrict__ P) {
  __shared__ alignas(16) f16 Xq[16 * 512];
  __shared__ float rowsum[16][8];
  const int tid = threadIdx.x;
  const int m0 = blockIdx.x * 16;
  const int w = tid >> 6, lane = tid & 63;
  const int lm = lane & 15, quad = lane >> 4;

  if (tid < 256) {
    int m = tid >> 4, oct = tid & 15;
    const float* src = X + (size_t)(m0 + m) * 128 + oct * 8;
    float4 a = reinterpret_cast<const float4*>(src)[0];
    float4 b = reinterpret_cast<const float4*>(src)[1];
    float xs[8] = {a.x, a.y, a.z, a.w, b.x, b.y, b.z, b.w};
    f16x8 vh, vl, v2h, v2l;
#pragma unroll
    for (int q = 0; q < 8; ++q) {
      float x = xs[q];
      f16 h = (f16)x;   f16 l = (f16)(x - (float)h);
      float x2 = x * x;
      f16 h2 = (f16)x2; f16 l2 = (f16)(x2 - (float)h2);
      vh[q] = h; vl[q] = l; v2h[q] = h2; v2l[q] = l2;
    }
    f16x8* row = reinterpret_cast<f16x8*>(&Xq[m * 512]);
    int sw = m & 7;
    row[(0 * 16 + oct) ^ sw] = v2h;
    row[(1 * 16 + oct) ^ sw] = v2l;
    row[(2 * 16 + oct) ^ sw] = vh;
    row[(3 * 16 + oct) ^ sw] = vl;
  }
  __syncthreads();

  f32x4 acc[2] = {};
  const f16x8* arow = reinterpret_cast<const f16x8*>(&Xq[lm * 512]);
  const int asw = lm & 7;
  const int col0 = w * 32 + lm;

#pragma unroll
  for (int t = 0; t < 24; ++t) {
    const int seg = t >> 2;
    const int plane = (seg < 2) ? 0 : (seg == 2) ? 1 : (seg < 5) ? 2 : 3;
    const int o = t * 4 + quad;
    f16x8 av = arow[(plane * 16 + (o & 15)) ^ asw];
    const f16* bp = Bext + ((size_t)o * 256 + col0) * 8;
    f16x8 b0 = *reinterpret_cast<const f16x8*>(bp);
    f16x8 b1 = *reinterpret_cast<const f16x8*>(bp + 16 * 8);
    acc[0] = __builtin_amdgcn_mfma_f32_16x16x32_f16(av, b0, acc[0], 0, 0, 0);
    acc[1] = __builtin_amdgcn_mfma_f32_16x16x32_f16(av, b1, acc[1], 0, 0, 0);
  }
  {
    f16x8 av = {};
    if (quad == 0) { av[0] = (f16)1.0f; av[1] = (f16)1.0f; }
    const int o = 96 + quad;
    const f16* bp = Bext + ((size_t)o * 256 + col0) * 8;
    f16x8 b0 = *reinterpret_cast<const f16x8*>(bp);
    f16x8 b1 = *reinterpret_cast<const f16x8*>(bp + 16 * 8);
    acc[0] = __builtin_amdgcn_mfma_f32_16x16x32_f16(av, b0, acc[0], 0, 0, 0);
    acc[1] = __builtin_amdgcn_mfma_f32_16x16x32_f16(av, b1, acc[1], 0, 0, 0);
  }

  float e[2][4];
#pragma unroll
  for (int nf = 0; nf < 2; ++nf)
#pragma unroll
    for (int q = 0; q < 4; ++q) e[nf][q] = __expf(acc[nf][q]);

  float rp[4];
#pragma unroll
  for (int q = 0; q < 4; ++q) {
    rp[q] = e[0][q] + e[1][q];
#pragma unroll
    for (int msk = 1; msk < 16; msk <<= 1) rp[q] += __shfl_xor(rp[q], msk, 64);
  }
  if (lm == 0)
#pragma unroll
    for (int q = 0; q < 4; ++q) rowsum[quad * 4 + q][w] = rp[q];
  __syncthreads();

#pragma unroll
  for (int q = 0; q < 4; ++q) {
    const int row = quad * 4 + q;
    float s8 = 0.f;
#pragma unroll
    for (int w2 = 0; w2 < 8; ++w2) s8 += rowsum[row][w2];
    const float inv = 1.0f / (s8 + 1e-8f);
#pragma unroll
    for (int nf = 0; nf < 2; ++nf)
      P[(size_t)(m0 + row) * R_RULES + w * 32 + nf * 16 + lm] =
          (f16)(e[nf][q] * inv);
  }
}

// ---------------------------------------------------------------------------
// Kernel 3: rules GEMM (R6 structure) with the Bs bank-conflict fix:
// read block index = quad ^ ((j>>1)&3)  (matches the swizzle baked into Cp).
// ---------------------------------------------------------------------------
__global__ __launch_bounds__(256) void anfis_main16(
    const float* __restrict__ X, const f16* __restrict__ P,
    const f16* __restrict__ Cp, float* __restrict__ part) {
  __shared__ alignas(16) f16 Xs[64 * KPAD];          // [m][i], 17408 B
  __shared__ alignas(16) f16 Bs[CH_I * 64 * 32];     // [ii][j][rg] 32768 B
  const int tid = threadIdx.x;
  const int g = blockIdx.x & 7;
  const int m0 = (blockIdx.x >> 3) * 64;
  const int w = tid >> 6, lane = tid & 63;
  const int mg = w >> 1, ng = w & 1;
  const int lm = lane & 15, quad = lane >> 4;

#pragma unroll
  for (int it = 0; it < 8; ++it) {
    int fi = tid + (it << 8);
    int m = fi >> 5, k4 = (fi & 31) << 2;
    float4 v = reinterpret_cast<const float4*>(X)[(size_t)(m0 + m) * 32 + (fi & 31)];
    f16x4 h = {(f16)v.x, (f16)v.y, (f16)v.z, (f16)v.w};
    *reinterpret_cast<f16x4*>(&Xs[m * KPAD + k4]) = h;
  }
  if (tid < 64) {
    f16x8 bias = {};
    bias[0] = (f16)1.0f;
    *reinterpret_cast<f16x8*>(&Xs[tid * KPAD + 128]) = bias;
  }

  union F8 { f16x8 v; f16x2 h[4]; };
  F8 pf[2];
#pragma unroll
  for (int mf = 0; mf < 2; ++mf) {
    int row = m0 + mg * 32 + mf * 16 + lm;
    pf[mf].v = *reinterpret_cast<const f16x8*>(
        &P[(size_t)row * R_RULES + g * 32 + quad * 8]);
  }

  f32x4 acc[2][2] = {};
  const char* cpg = (const char*)Cp + (size_t)g * KPAD * 4096;
  // swizzled B block offset: j = ng*32+lm (and j+16) share ((lm>>1)&3)
  const int bswz = (quad ^ ((lm >> 1) & 3)) * 8;

  for (int c = 0; c < NCHUNK; ++c) {
    __syncthreads();
    const char* gsrc = cpg + (size_t)c * 32768;
#pragma unroll
    for (int it = 0; it < 8; ++it) {
      int off = (it << 12) + (w << 10);
      __builtin_amdgcn_global_load_lds(
          (const __attribute__((address_space(1))) unsigned int*)(gsrc + off + lane * 16),
          (__attribute__((address_space(3))) unsigned int*)((char*)Bs + off),
          16, 0, 0);
    }
    __syncthreads();
    f16x8 xv[2];
    xv[0] = *reinterpret_cast<const f16x8*>(&Xs[(mg * 32 + lm) * KPAD + c * 8]);
    xv[1] = *reinterpret_cast<const f16x8*>(&Xs[(mg * 32 + 16 + lm) * KPAD + c * 8]);
#pragma unroll
    for (int ii = 0; ii < CH_I; ++ii) {
      F8 a[2];
#pragma unroll
      for (int mf = 0; mf < 2; ++mf) {
        f16 xvv = xv[mf][ii];
        f16x2 xd = {xvv, xvv};
        a[mf].h[0] = pf[mf].h[0] * xd;
        a[mf].h[1] = pf[mf].h[1] * xd;
        a[mf].h[2] = pf[mf].h[2] * xd;
        a[mf].h[3] = pf[mf].h[3] * xd;
      }
      const f16* brow = &Bs[(ii * 64 + ng * 32 + lm) * 32 + bswz];
      f16x8 b0 = *reinterpret_cast<const f16x8*>(brow);
      f16x8 b1 = *reinterpret_cast<const f16x8*>(brow + 16 * 32);
      acc[0][0] = __builtin_amdgcn_mfma_f32_16x16x32_f16(a[0].v, b0, acc[0][0], 0, 0, 0);
      acc[0][1] = __builtin_amdgcn_mfma_f32_16x16x32_f16(a[0].v, b1, acc[0][1], 0, 0, 0);
      acc[1][0] = __builtin_amdgcn_mfma_f32_16x16x32_f16(a[1].v, b0, acc[1][0], 0, 0, 0);
      acc[1][1] = __builtin_amdgcn_mfma_f32_16x16x32_f16(a[1].v, b1, acc[1][1], 0, 0, 0);
    }
  }

#pragma unroll
  for (int mf = 0; mf < 2; ++mf)
#pragma unroll
    for (int nf = 0; nf < 2; ++nf)
#pragma unroll
      for (int q = 0; q < 4; ++q) {
        int row = m0 + mg * 32 + mf * 16 + quad * 4 + q;
        int col = ng * 32 + nf * 16 + lm;
        part[((size_t)g * N_SAMPLES + row) * O_OUT + col] = acc[mf][nf][q];
      }
}

// ---------------------------------------------------------------------------
// Kernel 4 (R6 verbatim): sum 8 group partials + softmax over 64 outputs.
// ---------------------------------------------------------------------------
__global__ __launch_bounds__(256) void anfis_out(
    const float* __restrict__ part, float* __restrict__ out) {
  const int n = blockIdx.x * 4 + (threadIdx.x >> 6);
  const int lane = threadIdx.x & 63;
  const size_t stride = (size_t)N_SAMPLES * O_OUT;
  const float* p0 = part + (size_t)n * O_OUT + lane;
  float v = 0.f;
#pragma unroll
  for (int gg = 0; gg < 8; ++gg) v += p0[gg * stride];
  float mx = v;
#pragma unroll
  for (int off = 32; off; off >>= 1) mx = fmaxf(mx, __shfl_xor(mx, off, 64));
  float e = __expf(v - mx);
  float s = e;
#pragma unroll
  for (int off = 32; off; off >>= 1) s += __shfl_xor(s, off, 64);
  out[(size_t)n * O_OUT + lane] = e / s;
}

extern "C" void kernel_launch(void* const* d_in, const int* in_sizes, int n_in,
                              void* d_out, int out_size, void* d_ws, size_t ws_size,
                              hipStream_t stream) {
  const float* X       = (const float*)d_in[0];
  const float* centers = (const float*)d_in[1];
  const float* sigmas  = (const float*)d_in[2];
  const float* coeffs  = (const float*)d_in[3];
  float* out = (float*)d_out;

  float* part = (float*)d_ws;                                   // 8 MB
  f16*   Cp   = (f16*)(part + (size_t)NGROUPS * N_SAMPLES * O_OUT);
  f16*   Bext = Cp + (size_t)NGROUPS * KPAD * 2048;             // 400 KB
  f16*   P    = Bext + (size_t)100 * 256 * 8;                   // 2 MB

  anfis_prep_all<<<1088 + 128, 256, 0, stream>>>(coeffs, centers, sigmas, Cp, Bext);
  anfis_s16n<<<N_SAMPLES / 16, 512, 0, stream>>>(X, Bext, P);
  anfis_main16<<<512, 256, 0, stream>>>(X, P, Cp, part);
  anfis_out<<<N_SAMPLES / 4, 256, 0, stream>>>(part, out);
}